// Round 5
// baseline (159.778 us; speedup 1.0000x reference)
//
#include <hip/hip_runtime.h>
#include <cstdint>

// StreamNet K3 S1 halo conv, bf16 MFMA implicit-GEMM.
// R10: duty-cycle attack. R9 facts: (1) harness fill kernel hits 6.3 TB/s at
// 8.7% occupancy -> the 2.45 TB/s wall is NOT concurrency; (2) duty-cycle
// arithmetic: 2 phase-synchronized blocks/CU give {memory burst -> memory-idle
// compute tail}, duty ~39% = 2.43/6.3. Fix the duty cycle:
//   * 3 blocks/CU: LDS = X region only (41.7 KB), W overlaid in its low
//     4.6 KB; __launch_bounds__(256,3). Pair-interleaved staging keeps peak
//     regs ~150 < 168 cap (R7 lesson: spill = +traffic catastrophe).
//   * pack_w prologue kernel (9 blocks, ~2-3us) pre-packs W into d_ws in the
//     final bf16 LDS image: removes the div-by-9 + 36x ds_write_b16 repack
//     (~290 VALU ops/thread) from every block's tail, halves W bytes/block.
//   * W loads issued BEFORE X loads so the W ds_write's vmcnt wait (FIFO)
//     doesn't drain the X queue.
//   * keeps R9: 16x32 tiles (128B rows), grid 1024, XCD swizzle (batch i ->
//     XCD i), column-half-split MFMA sweep, plain f4 epilogue stores.
//
// Padded input Xp[b][c][r][cc], r,cc in [0,258):
//   r < 2           -> bbuf[b][c][r][cc]           (bbuf [B][C][2][258])
//   r>=2, cc < 2    -> rbuf[b][c][r-2][cc]         (rbuf [B][C][256][2])
//   r>=2, cc>=2     -> (cc-2 == 255) ? 0 : x[b][c][r-2][cc-2]

constexpr int B  = 8;
constexpr int C  = 32;
constexpr int P  = 256;
constexpr int KB = 2;
constexpr int TH = 16;            // tile rows
constexpr int TW = 32;            // tile cols
constexpr int RS = 36;            // LDS row stride (dwords); padded col pc stored at 2+pc
constexpr int PL = 652;           // plane stride (dwords); %32=12 (A reads 2-way free), %4=0
constexpr int XSZ = 16 * PL;      // 10432 dwords = 41728 B; low 4608 dw = W overlay

typedef short bf16x8 __attribute__((ext_vector_type(8)));
typedef float f32x4  __attribute__((ext_vector_type(4)));
union Frag { uint32_t u[4]; bf16x8 v; };

static __device__ __forceinline__ uint32_t pk_bf16(float lo, float hi) {
    uint32_t a  = __builtin_bit_cast(uint32_t, lo);
    uint32_t b2 = __builtin_bit_cast(uint32_t, hi);
    a  += 0x7FFFu + ((a  >> 16) & 1u);
    b2 += 0x7FFFu + ((b2 >> 16) & 1u);
    return (a >> 16) | (b2 & 0xFFFF0000u);
}

// ---- prologue: pack W [C][C][3][3] f32 -> bf16-pair LDS image in d_ws ----
// image dword index: t*512 + oc*16 + icpair, halves (lo,hi) = ic (2m, 2m+1)
__global__ __launch_bounds__(256) void pack_w_kernel(
    const float* __restrict__ W, uint32_t* __restrict__ wpk)
{
    const int g = blockIdx.x * 256 + threadIdx.x;      // 0..2303
    const float4 v = ((const float4*)W)[g];
    const float vv[4] = { v.x, v.y, v.z, v.w };
    uint16_t* wh = (uint16_t*)wpk;
    #pragma unroll
    for (int e = 0; e < 4; ++e) {
        const int flat = 4 * g + e;                    // (oc*32+ic)*9 + t
        const int t    = flat % 9;
        const int rest = flat / 9;
        const int ic   = rest & 31;
        const int oc   = rest >> 5;
        const uint32_t u = __builtin_bit_cast(uint32_t, vv[e]);
        const uint16_t h = (uint16_t)((u + 0x7FFFu + ((u >> 16) & 1u)) >> 16);
        wh[(t * 512 + oc * 16 + (ic >> 1)) * 2 + (ic & 1)] = h;
    }
}

struct StP {                       // one plane-pair's staged data
    float4 a0, a1, c0, c1;         // interior: lo plane 8 cols, hi plane 8 cols
    float  h0l, h0h, h1l, h1h;     // 2 halo cells x (lo, hi)
};

__global__ __launch_bounds__(256, 3) void conv_mfma(
    const float* __restrict__ x,      // [B][C][P][P]
    const float* __restrict__ rbuf,   // [B][C][P][KB]
    const float* __restrict__ bbuf,   // [B][C][KB][P+KB]
    const uint32_t* __restrict__ wpk, // packed W image (4608 dwords)
    const float* __restrict__ bias,   // [C]
    float* __restrict__ out)          // [B][C][P][P]
{
    const int tid  = threadIdx.x;
    const int lane = tid & 63;
    const int w    = tid >> 6;        // wave 0..3
    const int q    = lane >> 4;
    const int n16  = lane & 15;

    // XCD swizzle: round-robin dispatch (blk%8 = XCD) -> XCD i gets swz
    // range [128i,128(i+1)) = all tiles of batch i (8.4MB x, in-XCD halos)
    const int swz = (blockIdx.x & 7) * 128 + (blockIdx.x >> 3);
    const int cx = swz & 7, ty = (swz >> 3) & 15, b = swz >> 7;
    const int x0 = cx * TW, y0 = ty * TH;

    __shared__ uint32_t Xs[XSZ];      // low 4608 dwords double as W region first

    // ---- staging lane geometry ----
    const int srow = lane >> 2;                    // 0..15
    const int scol = (lane & 3) * 8;               // 0,8,16,24 (8 cols/lane)
    const bool zc  = (x0 == P - TW) && ((lane & 3) == 3);   // col 255 in a1.w/c1.w

    // halo cells: 100 = top 2x34 (idx 0..67) + left 16x2 (idx 68..99)
    const float* xb = x    + (size_t)b * C * P * P;
    const float* rb = rbuf + (size_t)b * C * P * KB;
    const float* bb = bbuf + (size_t)b * C * KB * (P + KB);
    const float* basep[3] = { xb, rb, bb };
    const int    psz[3]   = { P * P, P * KB, KB * (P + KB) };

    int h_ldso[2], h_ps[2];
    const float* h_bp[2];
    bool h_z[2];
    #pragma unroll
    for (int ci = 0; ci < 2; ++ci) {
        const int c = lane + 64 * ci;
        int prow, pcol;
        if (c < 68) { const int hr = (c >= 34) ? 1 : 0; prow = hr; pcol = c - 34 * hr; }
        else        { const int cc = c - 68; prow = KB + (cc >> 1); pcol = cc & 1; }
        h_ldso[ci] = prow * RS + 2 + pcol;
        const int gr = y0 + prow, gc = x0 + pcol;
        int sel, off; bool z = false;
        if (gr < KB)      { sel = 2; off = gr * (P + KB) + gc; }
        else if (gc < KB) { sel = 1; off = (gr - KB) * KB + gc; }
        else              { sel = 0; off = (gr - KB) * P + (gc - KB); z = (gc == P + KB - 1); }
        h_bp[ci] = basep[sel] + off;
        h_ps[ci] = psz[sel];
        h_z[ci]  = z;
    }
    const bool h1a = lane < 36;                    // cell1 active

    auto ld = [&](int m, StP& S) {
        const float* pi = xb + (size_t)(2 * m) * (P * P) + (y0 + srow) * P + x0 + scol;
        S.a0 = *(const float4*)pi;
        S.a1 = *(const float4*)(pi + 4);
        S.c0 = *(const float4*)(pi + P * P);
        S.c1 = *(const float4*)(pi + P * P + 4);
        const float* p0 = h_bp[0] + (size_t)(2 * m) * h_ps[0];
        S.h0l = h_z[0] ? 0.f : p0[0];
        S.h0h = h_z[0] ? 0.f : p0[h_ps[0]];
        if (h1a) {
            const float* p1 = h_bp[1] + (size_t)(2 * m) * h_ps[1];
            S.h1l = h_z[1] ? 0.f : p1[0];
            S.h1h = h_z[1] ? 0.f : p1[h_ps[1]];
        }
    };

    auto st = [&](int m, StP& S) {
        float4 a1 = S.a1, c1 = S.c1;
        if (zc) { a1.w = 0.f; c1.w = 0.f; }
        uint4 u0, u1;
        u0.x = pk_bf16(S.a0.x, S.c0.x); u0.y = pk_bf16(S.a0.y, S.c0.y);
        u0.z = pk_bf16(S.a0.z, S.c0.z); u0.w = pk_bf16(S.a0.w, S.c0.w);
        u1.x = pk_bf16(a1.x, c1.x);     u1.y = pk_bf16(a1.y, c1.y);
        u1.z = pk_bf16(a1.z, c1.z);     u1.w = pk_bf16(a1.w, c1.w);
        uint32_t* base = Xs + m * PL + (srow + KB) * RS + 4 + scol;  // 16B aligned
        *(uint4*)base       = u0;
        *(uint4*)(base + 4) = u1;
        Xs[m * PL + h_ldso[0]] = pk_bf16(S.h0l, S.h0h);
        if (h1a) Xs[m * PL + h_ldso[1]] = pk_bf16(S.h1l, S.h1h);
    };

    // ---- 1. W image loads FIRST (so their ds_write waits only on them) ----
    const uint4* wp4 = (const uint4*)wpk;          // 1152 uint4
    uint4 wv0 = wp4[tid];
    uint4 wv1 = wp4[256 + tid];
    uint4 wv2 = wp4[512 + tid];
    uint4 wv3 = wp4[768 + tid];
    uint4 wvt;
    const bool wtail = tid < 128;
    if (wtail) wvt = wp4[1024 + tid];
    const float bv0 = bias[n16];
    const float bv1 = bias[16 + n16];

    // ---- 2. issue X loads for pairs p0 (m=w), p1 (m=4+w) ----
    StP S0, S1, S2, S3;
    ld(w, S0);
    ld(4 + w, S1);

    // ---- 3. W image -> LDS overlay (waits vmcnt only to W loads) ----
    uint4* xs4 = (uint4*)Xs;
    xs4[tid]       = wv0;
    xs4[256 + tid] = wv1;
    xs4[512 + tid] = wv2;
    xs4[768 + tid] = wv3;
    if (wtail) xs4[1024 + tid] = wvt;
    __syncthreads();

    // ---- 4. B fragments from overlay ----
    Frag Bf[9][2];
    #pragma unroll
    for (int t = 0; t < 9; ++t)
        #pragma unroll
        for (int oh = 0; oh < 2; ++oh)
            *(uint4*)Bf[t][oh].u =
                *(const uint4*)&Xs[t * 512 + (oh * 16 + n16) * 16 + q * 4];
    __syncthreads();              // overlay reads done; Xs reusable for X tile

    // ---- 5. pair-interleaved stage: st(k) || ld(k+2) ----
    st(w, S0);        ld(8 + w, S2);
    st(4 + w, S1);    ld(12 + w, S3);
    st(8 + w, S2);
    st(12 + w, S3);
    __syncthreads();

    // ---- 6. MFMA sweep, split by column-half ch (acc stays 32 f32) ----
    #pragma unroll
    for (int ch = 0; ch < 2; ++ch) {
        f32x4 acc[4][2];
        #pragma unroll
        for (int rr = 0; rr < 4; ++rr)
            #pragma unroll
            for (int oh = 0; oh < 2; ++oh)
                #pragma unroll
                for (int e = 0; e < 4; ++e) acc[rr][oh][e] = 0.f;

        // A-frags deduped: padded row 4w+dr serves all (rr,ky) with rr+ky==dr
        #pragma unroll
        for (int dr = 0; dr < 6; ++dr) {
            Frag A[3];
            const uint32_t* ap = Xs + (4 * q) * PL + (4 * w + dr) * RS + 2 + 16 * ch + n16;
            #pragma unroll
            for (int kx = 0; kx < 3; ++kx)
                #pragma unroll
                for (int p = 0; p < 4; ++p)
                    A[kx].u[p] = ap[p * PL + kx];
            #pragma unroll
            for (int ky = 0; ky < 3; ++ky) {
                const int rr = dr - ky;
                if (rr >= 0 && rr < 4) {
                    #pragma unroll
                    for (int kx = 0; kx < 3; ++kx) {
                        acc[rr][0] = __builtin_amdgcn_mfma_f32_16x16x32_bf16(
                                         A[kx].v, Bf[ky * 3 + kx][0].v, acc[rr][0], 0, 0, 0);
                        acc[rr][1] = __builtin_amdgcn_mfma_f32_16x16x32_bf16(
                                         A[kx].v, Bf[ky * 3 + kx][1].v, acc[rr][1], 0, 0, 0);
                    }
                }
            }
        }

        // ---- epilogue for this ch: plain float4 stores (L2 merges halves) ----
        #pragma unroll
        for (int oh = 0; oh < 2; ++oh) {
            const int oc = oh * 16 + n16;
            const float bv = oh ? bv1 : bv0;
            #pragma unroll
            for (int rr = 0; rr < 4; ++rr) {
                float4 v;
                v.x = acc[rr][oh][0] + bv;
                v.y = acc[rr][oh][1] + bv;
                v.z = acc[rr][oh][2] + bv;
                v.w = acc[rr][oh][3] + bv;
                *(float4*)&out[((size_t)(b * C + oc) * P + (y0 + 4 * w + rr)) * P
                               + x0 + 16 * ch + 4 * q] = v;
            }
        }
    }
}

extern "C" void kernel_launch(void* const* d_in, const int* in_sizes, int n_in,
                              void* d_out, int out_size, void* d_ws, size_t ws_size,
                              hipStream_t stream) {
    const float* x    = (const float*)d_in[0];
    const float* rbuf = (const float*)d_in[1];
    const float* bbuf = (const float*)d_in[2];
    const float* W    = (const float*)d_in[3];
    const float* bias = (const float*)d_in[4];
    float* out = (float*)d_out;
    uint32_t* wpk = (uint32_t*)d_ws;              // 18432 B used

    pack_w_kernel<<<9, 256, 0, stream>>>(W, wpk);
    conv_mfma<<<1024, 256, 0, stream>>>(x, rbuf, bbuf, wpk, bias, out);
}